// Round 19
// baseline (89.869 us; speedup 1.0000x reference)
//
#include <hip/hip_runtime.h>

#define NT 256

typedef unsigned int uint;
typedef unsigned short ushort_t;
typedef float f2 __attribute__((ext_vector_type(2)));
typedef short bh8 __attribute__((ext_vector_type(8)));
typedef float f32x4 __attribute__((ext_vector_type(4)));
typedef uint u32x4 __attribute__((ext_vector_type(4)));

// ---- async global->LDS 16B; HW adds lane*16 to the wave-uniform LDS base ----
__device__ __forceinline__ void gload16(const float* g, float* l) {
  __builtin_amdgcn_global_load_lds(
      (const __attribute__((address_space(1))) void*)g,
      (__attribute__((address_space(3))) void*)l, 16, 0, 0);
}

// ---------- f32 -> bf16 hi/lo split (double truncation, rel err ~2^-16) ----------
__device__ __forceinline__ uint hi2(float a, float b) {
  return (__float_as_uint(a) >> 16) | (__float_as_uint(b) & 0xffff0000u);
}
__device__ __forceinline__ uint lo2(float a, float b) {
  const float r0 = a - __uint_as_float(__float_as_uint(a) & 0xffff0000u);
  const float r1 = b - __uint_as_float(__float_as_uint(b) & 0xffff0000u);
  return hi2(r0, r1);
}
__device__ __forceinline__ void split8v(float4 v0, float4 v1, bh8& hi, bh8& lo) {
  u32x4 h = {hi2(v0.x, v0.y), hi2(v0.z, v0.w), hi2(v1.x, v1.y), hi2(v1.z, v1.w)};
  u32x4 t = {lo2(v0.x, v0.y), lo2(v0.z, v0.w), lo2(v1.x, v1.y), lo2(v1.z, v1.w)};
  hi = __builtin_bit_cast(bh8, h);
  lo = __builtin_bit_cast(bh8, t);
}

// ================= meta body with IN-BLOCK vout (proven r14/r15) =================
__device__ __forceinline__ void meta_body(
    int g,
    const float* __restrict__ w1, const float* __restrict__ w2, const float* __restrict__ w3,
    const float* __restrict__ a0, const float* __restrict__ r1, const float* __restrict__ r2,
    const float* __restrict__ bb1, const float* __restrict__ bb2, const float* __restrict__ bb3,
    float* __restrict__ n1, float* __restrict__ n2, float* __restrict__ n3,
    const float* __restrict__ mw1, const float* __restrict__ mb1,
    const float* __restrict__ mw2, const float* __restrict__ mb2) {
  const int n1c = (2048 * 1024) / 8;
  const int n2c = (2048 * 2048) / 8;

  const float* W; const float* vin; const float* bias; float* nw;
  int sh, e;
  if (g < n1c)            { W = w1; vin = a0; bias = bb1; nw = n1; sh = 10; e = g; }
  else if (g < n1c + n2c) { W = w2; vin = r1; bias = bb2; nw = n2; sh = 11; e = g - n1c; }
  else                    { W = w3; vin = r2; bias = bb3; nw = n3; sh = 11; e = g - n1c - n2c; }

  const int base = e << 3;
  const int o = base >> sh;
  const int i0 = base & ((1 << sh) - 1);
  const int tid = threadIdx.x;

  f2 wv[4], vv[4];
  {
    float4 t0 = *reinterpret_cast<const float4*>(&W[base]);
    float4 t1 = *reinterpret_cast<const float4*>(&W[base + 4]);
    wv[0] = (f2){t0.x, t0.y}; wv[1] = (f2){t0.z, t0.w};
    wv[2] = (f2){t1.x, t1.y}; wv[3] = (f2){t1.z, t1.w};
    float4 u0 = *reinterpret_cast<const float4*>(&vin[i0]);
    float4 u1 = *reinterpret_cast<const float4*>(&vin[i0 + 4]);
    vv[0] = (f2){u0.x, u0.y}; vv[1] = (f2){u0.z, u0.w};
    vv[2] = (f2){u1.x, u1.y}; vv[3] = (f2){u1.z, u1.w};
  }

  // in-block vout: per-thread partial dot, wave reduce, LDS combine
  float part = 0.f;
  #pragma unroll
  for (int p = 0; p < 4; ++p)
    part += wv[p].x * vv[p].x + wv[p].y * vv[p].y;
  #pragma unroll
  for (int m = 32; m >= 1; m >>= 1)
    part += __shfl_xor(part, m, 64);
  __shared__ float msum[4];
  if ((tid & 63) == 0) msum[tid >> 6] = part;
  __syncthreads();
  float vo;
  if (sh == 10) vo = (tid < 128) ? (msum[0] + msum[1]) : (msum[2] + msum[3]);
  else          vo = (msum[0] + msum[1]) + (msum[2] + msum[3]);
  vo = fmaxf(vo + bias[o], 0.f);

  const float c2 = mb2[0];
  float r[32];
  #pragma unroll
  for (int j = 0; j < 32; ++j)
    r[j] = fmaf(mw1[3 * j + 2], vo, mb1[j]);

  f2 acc[4];
  #pragma unroll
  for (int p = 0; p < 4; ++p) acc[p] = (f2){c2, c2};

  const f2 zero = (f2){0.f, 0.f};
  #pragma unroll
  for (int j = 0; j < 32; ++j) {
    const float aj = mw1[3 * j];
    const float bj = mw1[3 * j + 1];
    const float mj = mw2[j];
    const f2 a2v = (f2){aj, aj};
    const f2 b2v = (f2){bj, bj};
    const f2 m2v = (f2){mj, mj};
    const f2 r2v = (f2){r[j], r[j]};
    #pragma unroll
    for (int p = 0; p < 4; ++p) {
#if __has_builtin(__builtin_elementwise_fma) && __has_builtin(__builtin_elementwise_max)
      f2 q = __builtin_elementwise_fma(a2v, vv[p], r2v);
      f2 h = __builtin_elementwise_fma(b2v, wv[p], q);
      h = __builtin_elementwise_max(h, zero);
      acc[p] = __builtin_elementwise_fma(m2v, h, acc[p]);
#else
      f2 h;
      h.x = fmaxf(fmaf(bj, wv[p].x, fmaf(aj, vv[p].x, r[j])), 0.f);
      h.y = fmaxf(fmaf(bj, wv[p].y, fmaf(aj, vv[p].y, r[j])), 0.f);
      acc[p].x = fmaf(mj, h.x, acc[p].x);
      acc[p].y = fmaf(mj, h.y, acc[p].y);
#endif
    }
  }

  *reinterpret_cast<float4*>(&nw[base])     = make_float4(acc[0].x, acc[0].y, acc[1].x, acc[1].y);
  *reinterpret_cast<float4*>(&nw[base + 4]) = make_float4(acc[2].x, acc[2].y, acc[3].x, acc[3].y);
}

// ================= gemv: single-row activation chain (proven r11) =================
__device__ __forceinline__ void gemv_body(
    int lbid, int tid,
    const float* __restrict__ vX, const float* __restrict__ vW,
    const float* __restrict__ vB, float* __restrict__ vR, int vK) {
  const int w = tid >> 6, l = tid & 63;
  const int obase = lbid * 16 + w * 4;
  const int nt = vK >> 8;
  float4 xv[8];
  #pragma unroll 8
  for (int t = 0; t < nt; ++t)
    xv[t] = *reinterpret_cast<const float4*>(&vX[(l + (t << 6)) << 2]);
  #pragma unroll
  for (int q = 0; q < 4; ++q) {
    const int o = obase + q;
    const float* wr = vW + (size_t)o * vK;
    float a = 0.f;
    #pragma unroll 8
    for (int t = 0; t < nt; ++t) {
      const float4 wv = *reinterpret_cast<const float4*>(&wr[(l + (t << 6)) << 2]);
      a = fmaf(wv.x, xv[t].x, a); a = fmaf(wv.y, xv[t].y, a);
      a = fmaf(wv.z, xv[t].z, a); a = fmaf(wv.w, xv[t].w, a);
    }
    #pragma unroll
    for (int m = 32; m >= 1; m >>= 1)
      a += __shfl_xor(a, m, 64);
    if (l == 0) vR[o] = fmaxf(a + vB[o], 0.f);
  }
}

// ================= MFMA gemm, split-K S=8, LDS-staged W (r12 body + A-on-the-fly) =====
// AMODE 0: A = f32 matrix (x). AMODE 1: A built on the fly from prev-layer partials:
//   a[b][k] = relu( sum_{sl<8} Pprev[sl][b][k] + Abias[k] )   (Pprev is L2/L3-resident)
template<int KL, int OBL, int AMODE>
__device__ __forceinline__ void gemm_fwd(
    int gb, int tid,
    const float* __restrict__ Asrc, const float* __restrict__ Abias,
    const float* __restrict__ W, int K, int O,
    float* __restrict__ P, float* __restrict__ Wt) {
  const int ob = gb & ((1 << OBL) - 1);
  const int sl = gb >> OBL;
  const int w = tid >> 6, l = tid & 63;
  const int l15 = l & 15, lk = l >> 4;
  const int b0 = (w & 1) << 4;
  const int ow = (w >> 1) << 6;
  const int obase = ob << 7;
  const int kbeg = sl * KL;
  const int bA = b0 + l15;

  f32x4 acc[4];
  #pragma unroll
  for (int of = 0; of < 4; ++of)
    #pragma unroll
    for (int e = 0; e < 4; ++e) acc[of][e] = 0.f;

  #pragma unroll 1
  for (int c = 0; c < KL / 32; ++c) {
    const int kc = kbeg + (c << 5);
    const int kk = kc + (lk << 3);
    bh8 ahi, alo;
    if constexpr (AMODE == 0) {
      const float4 v0 = *reinterpret_cast<const float4*>(&Asrc[(size_t)bA * K + kk]);
      const float4 v1 = *reinterpret_cast<const float4*>(&Asrc[(size_t)bA * K + kk + 4]);
      split8v(v0, v1, ahi, alo);
    } else {
      float4 s0 = *reinterpret_cast<const float4*>(&Abias[kk]);
      float4 s1 = *reinterpret_cast<const float4*>(&Abias[kk + 4]);
      #pragma unroll
      for (int q2 = 0; q2 < 8; ++q2) {
        const float* pp = &Asrc[((size_t)(q2 * 32) + bA) * K + kk];
        const float4 p0 = *reinterpret_cast<const float4*>(pp);
        const float4 p1 = *reinterpret_cast<const float4*>(pp + 4);
        s0.x += p0.x; s0.y += p0.y; s0.z += p0.z; s0.w += p0.w;
        s1.x += p1.x; s1.y += p1.y; s1.z += p1.z; s1.w += p1.w;
      }
      s0.x = fmaxf(s0.x, 0.f); s0.y = fmaxf(s0.y, 0.f);
      s0.z = fmaxf(s0.z, 0.f); s0.w = fmaxf(s0.w, 0.f);
      s1.x = fmaxf(s1.x, 0.f); s1.y = fmaxf(s1.y, 0.f);
      s1.z = fmaxf(s1.z, 0.f); s1.w = fmaxf(s1.w, 0.f);
      split8v(s0, s1, ahi, alo);
    }
    // stage W chunk [128][32] f32 via global_load_lds, source pre-swizzled (proven)
    #pragma unroll
    for (int q = 0; q < 4; ++q) {
      const int s = (q << 8) + tid;              // float4-slot 0..1023
      const int r = s >> 3;                      // row 0..127
      const int p = s & 7;                       // stored slot
      const float* gp = &W[(size_t)(obase + r) * K + kc + ((p ^ (r & 7)) << 2)];
      gload16(gp, Wt + ((s & ~63) << 2));        // wave-uniform base; HW adds lane*16
    }
    __syncthreads();

    #pragma unroll
    for (int of = 0; of < 4; ++of) {
      const int lr = ow + (of << 4) + l15;
      const int cb = lk << 1;
      const float4 w0 = *reinterpret_cast<const float4*>(
          &Wt[(lr << 5) + ((cb ^ (lr & 7)) << 2)]);
      const float4 w1 = *reinterpret_cast<const float4*>(
          &Wt[(lr << 5) + (((cb + 1) ^ (lr & 7)) << 2)]);
      bh8 whi, wlo;
      split8v(w0, w1, whi, wlo);
      acc[of] = __builtin_amdgcn_mfma_f32_16x16x32_bf16(ahi, whi, acc[of], 0, 0, 0);
      acc[of] = __builtin_amdgcn_mfma_f32_16x16x32_bf16(ahi, wlo, acc[of], 0, 0, 0);
      acc[of] = __builtin_amdgcn_mfma_f32_16x16x32_bf16(alo, whi, acc[of], 0, 0, 0);
    }
    __syncthreads();
  }

  #pragma unroll
  for (int of = 0; of < 4; ++of) {
    const int o = obase + ow + (of << 4) + l15;
    #pragma unroll
    for (int r = 0; r < 4; ++r) {
      const int b = b0 + lk * 4 + r;
      P[((size_t)sl * 32 + b) * O + o] = acc[of][r];
    }
  }
}

// ================= fused role kernel: gemm | gemv | meta =================
template<int KL, int OBL, int AMODE>
__global__ __launch_bounds__(NT) void fusedK(
    int nGemm, const float* Asrc, const float* Abias, const float* W, int K, int O, float* P,
    int nGemv, const float* vX, const float* vW, const float* vB, float* vR, int vK,
    int mStart,
    const float* w1, const float* w2, const float* w3,
    const float* a0, const float* r1, const float* r2,
    const float* bb1, const float* bb2, const float* bb3,
    float* n1, float* n2, float* n3,
    const float* mw1, const float* mb1, const float* mw2, const float* mb2) {
  const int bid = blockIdx.x;
  const int tid = threadIdx.x;
  if (bid < nGemm) {
    __shared__ float Wt[128 * 32];   // 16 KB; 160/16 = 10 >= HW 8 blk/CU -> no cap
    gemm_fwd<KL, OBL, AMODE>(bid, tid, Asrc, Abias, W, K, O, P, Wt);
    return;
  }
  int b = bid - nGemm;
  if (b < nGemv) { gemv_body(b, tid, vX, vW, vB, vR, vK); return; }
  b -= nGemv;
  const int g = (mStart + b) * NT + tid;
  meta_body(g, w1, w2, w3, a0, r1, r2, bb1, bb2, bb3,
            n1, n2, n3, mw1, mb1, mw2, mb2);
}

// ================= final reduce: P3 (8 slices) -> out f32 =================
__global__ __launch_bounds__(NT) void red3k(
    const float* __restrict__ P, const float* __restrict__ bias,
    float* __restrict__ outF) {
  const int idx = blockIdx.x * NT + threadIdx.x;   // 0..32767
  const int b = idx >> 10;
  const int o = idx & 1023;
  float s = 0.f;
  #pragma unroll
  for (int sl = 0; sl < 8; ++sl)
    s += P[(size_t)((sl * 32 + b) << 10) + o];
  outF[(size_t)(b << 10) + o] = fmaxf(s + bias[o], 0.f);
}

extern "C" void kernel_launch(void* const* d_in, const int* in_sizes, int n_in,
                              void* d_out, int out_size, void* d_ws, size_t ws_size,
                              hipStream_t stream) {
  const float* x   = (const float*)d_in[0];
  const float* w1  = (const float*)d_in[1];
  const float* b1  = (const float*)d_in[2];
  const float* w2  = (const float*)d_in[3];
  const float* b2  = (const float*)d_in[4];
  const float* w3  = (const float*)d_in[5];
  const float* b3  = (const float*)d_in[6];
  const float* mw1 = (const float*)d_in[7];
  const float* mb1 = (const float*)d_in[8];
  const float* mw2 = (const float*)d_in[9];
  const float* mb2 = (const float*)d_in[10];

  float* out = (float*)d_out;                 // [32][1024]
  float* n1  = out + 32 * 1024;               // [2048][1024]
  float* n2  = n1 + 2048 * 1024;              // [2048][2048]
  float* n3  = n2 + 2048 * 2048;              // [1024][2048]

  float* ws = (float*)d_ws;
  float* row01 = ws;                          // 2048 (a1 row 0, f32)
  float* row02 = row01 + 2048;                // 2048 (a2 row 0, f32)
  float* P1 = row02 + 2048;                   // [8][32][2048] 2 MB
  float* P2 = P1 + 524288;                    // [8][32][2048] 2 MB
  float* P3 = P2 + 524288;                    // [8][32][1024] 1 MB

  // meta vb space: layer1 [0,1024) | layer2 [1024,3072) | layer3 [3072,4096)
  #define MARGS w1, w2, w3, x, row01, row02, b1, b2, b3, n1, n2, n3, mw1, mb1, mw2, mb2

  // K1: gemm1 x@w1 -> P1 (128 = 16 otiles x 8 slices, KL=128)
  //     || gemv1 w1@x0 -> row01 (128) || meta1 (1024, in-block vout from x,w1)
  fusedK<128, 4, 0><<<1280, NT, 0, stream>>>(
      128, x, nullptr, w1, 1024, 2048, P1,
      128, x, w1, b1, row01, 1024,
      0, MARGS);

  // K2: gemm2 (A on-the-fly from P1+b1) @ w2 -> P2 (128, KL=256)
  //     || gemv2 w2@row01 -> row02 (128) || meta2 (2048, vin=row01)
  fusedK<256, 4, 1><<<2304, NT, 0, stream>>>(
      128, P1, b1, w2, 2048, 2048, P2,
      128, row01, w2, b2, row02, 2048,
      1024, MARGS);

  // K3: gemm3 (A on-the-fly from P2+b2) @ w3 -> P3 (64 = 8 otiles x 8 slices, KL=256)
  //     || meta3 (1024, vin=row02)
  fusedK<256, 3, 1><<<1088, NT, 0, stream>>>(
      64, P2, b2, w3, 2048, 1024, P3,
      0, nullptr, nullptr, nullptr, nullptr, 0,
      3072, MARGS);

  // K4: red3 P3 -> out f32 (128 blocks, tiny)
  red3k<<<128, NT, 0, stream>>>(P3, b3, out);

  #undef MARGS
}

// Round 20
// 50.814 us; speedup vs baseline: 1.7686x; 1.7686x over previous
//
#include <hip/hip_runtime.h>

#define NT 256

typedef unsigned int uint;
typedef unsigned short ushort_t;
typedef float f2 __attribute__((ext_vector_type(2)));
typedef short bh8 __attribute__((ext_vector_type(8)));
typedef float f32x4 __attribute__((ext_vector_type(4)));
typedef uint u32x4 __attribute__((ext_vector_type(4)));

// ---- async global->LDS 16B; HW adds lane*16 to the wave-uniform LDS base ----
__device__ __forceinline__ void gload16(const float* g, float* l) {
  __builtin_amdgcn_global_load_lds(
      (const __attribute__((address_space(1))) void*)g,
      (__attribute__((address_space(3))) void*)l, 16, 0, 0);
}

// ---------- f32 -> bf16 hi/lo split (double truncation, rel err ~2^-16) ----------
__device__ __forceinline__ uint hi2(float a, float b) {
  return (__float_as_uint(a) >> 16) | (__float_as_uint(b) & 0xffff0000u);
}
__device__ __forceinline__ uint lo2(float a, float b) {
  const float r0 = a - __uint_as_float(__float_as_uint(a) & 0xffff0000u);
  const float r1 = b - __uint_as_float(__float_as_uint(b) & 0xffff0000u);
  return hi2(r0, r1);
}
__device__ __forceinline__ void split8v(float4 v0, float4 v1, bh8& hi, bh8& lo) {
  u32x4 h = {hi2(v0.x, v0.y), hi2(v0.z, v0.w), hi2(v1.x, v1.y), hi2(v1.z, v1.w)};
  u32x4 t = {lo2(v0.x, v0.y), lo2(v0.z, v0.w), lo2(v1.x, v1.y), lo2(v1.z, v1.w)};
  hi = __builtin_bit_cast(bh8, h);
  lo = __builtin_bit_cast(bh8, t);
}

// ================= meta body (proven) =================
__device__ __forceinline__ void meta_body(
    int g,
    const float* __restrict__ w1, const float* __restrict__ w2, const float* __restrict__ w3,
    const float* __restrict__ a0, const float* __restrict__ a1, const float* __restrict__ a2,
    const float* __restrict__ a3,
    float* __restrict__ n1, float* __restrict__ n2, float* __restrict__ n3,
    const float* __restrict__ mw1, const float* __restrict__ mb1,
    const float* __restrict__ mw2, const float* __restrict__ mb2) {
  const int n1c = (2048 * 1024) / 8;
  const int n2c = (2048 * 2048) / 8;

  const float* W; const float* vin; const float* vout; float* nw;
  int sh, e;
  if (g < n1c)            { W = w1; vin = a0; vout = a1; nw = n1; sh = 10; e = g; }
  else if (g < n1c + n2c) { W = w2; vin = a1; vout = a2; nw = n2; sh = 11; e = g - n1c; }
  else                    { W = w3; vin = a2; vout = a3; nw = n3; sh = 11; e = g - n1c - n2c; }

  const int base = e << 3;
  const int o = base >> sh;
  const int i0 = base & ((1 << sh) - 1);

  f2 wv[4], vv[4];
  {
    float4 t0 = *reinterpret_cast<const float4*>(&W[base]);
    float4 t1 = *reinterpret_cast<const float4*>(&W[base + 4]);
    wv[0] = (f2){t0.x, t0.y}; wv[1] = (f2){t0.z, t0.w};
    wv[2] = (f2){t1.x, t1.y}; wv[3] = (f2){t1.z, t1.w};
    float4 u0 = *reinterpret_cast<const float4*>(&vin[i0]);
    float4 u1 = *reinterpret_cast<const float4*>(&vin[i0 + 4]);
    vv[0] = (f2){u0.x, u0.y}; vv[1] = (f2){u0.z, u0.w};
    vv[2] = (f2){u1.x, u1.y}; vv[3] = (f2){u1.z, u1.w};
  }
  const float vo = vout[o];
  const float c2 = mb2[0];

  float r[32];
  #pragma unroll
  for (int j = 0; j < 32; ++j)
    r[j] = fmaf(mw1[3 * j + 2], vo, mb1[j]);

  f2 acc[4];
  #pragma unroll
  for (int p = 0; p < 4; ++p) acc[p] = (f2){c2, c2};

  const f2 zero = (f2){0.f, 0.f};
  #pragma unroll
  for (int j = 0; j < 32; ++j) {
    const float aj = mw1[3 * j];
    const float bj = mw1[3 * j + 1];
    const float mj = mw2[j];
    const f2 a2v = (f2){aj, aj};
    const f2 b2v = (f2){bj, bj};
    const f2 m2v = (f2){mj, mj};
    const f2 r2v = (f2){r[j], r[j]};
    #pragma unroll
    for (int p = 0; p < 4; ++p) {
#if __has_builtin(__builtin_elementwise_fma) && __has_builtin(__builtin_elementwise_max)
      f2 q = __builtin_elementwise_fma(a2v, vv[p], r2v);
      f2 h = __builtin_elementwise_fma(b2v, wv[p], q);
      h = __builtin_elementwise_max(h, zero);
      acc[p] = __builtin_elementwise_fma(m2v, h, acc[p]);
#else
      f2 h;
      h.x = fmaxf(fmaf(bj, wv[p].x, fmaf(aj, vv[p].x, r[j])), 0.f);
      h.y = fmaxf(fmaf(bj, wv[p].y, fmaf(aj, vv[p].y, r[j])), 0.f);
      acc[p].x = fmaf(mj, h.x, acc[p].x);
      acc[p].y = fmaf(mj, h.y, acc[p].y);
#endif
    }
  }

  *reinterpret_cast<float4*>(&nw[base])     = make_float4(acc[0].x, acc[0].y, acc[1].x, acc[1].y);
  *reinterpret_cast<float4*>(&nw[base + 4]) = make_float4(acc[2].x, acc[2].y, acc[3].x, acc[3].y);
}

// ================= MFMA gemm with LDS-staged W (proven) =================
// Block: 4 waves, tile 128o x 32b, split-K 16 slices, 32-k chunks.
template<int KL, int OBL, int AF32>
__device__ __forceinline__ void gemm_fwd(
    int gb, int tid,
    const float* __restrict__ Af32, const ushort_t* __restrict__ Ahi,
    const ushort_t* __restrict__ Alo,
    const float* __restrict__ W, int K, int O,
    float* __restrict__ P, float* __restrict__ Wt) {
  const int ob = gb & ((1 << OBL) - 1);
  const int sl = gb >> OBL;
  const int w = tid >> 6, l = tid & 63;
  const int l15 = l & 15, lk = l >> 4;
  const int b0 = (w & 1) << 4;
  const int ow = (w >> 1) << 6;
  const int obase = ob << 7;
  const int kbeg = sl * KL;
  const int bA = b0 + l15;

  f32x4 acc[4];
  #pragma unroll
  for (int of = 0; of < 4; ++of)
    #pragma unroll
    for (int e = 0; e < 4; ++e) acc[of][e] = 0.f;

  #pragma unroll 1
  for (int c = 0; c < KL / 32; ++c) {
    const int kc = kbeg + (c << 5);
    bh8 ahi, alo;
    const int kk = kc + (lk << 3);
    if constexpr (AF32) {
      const float4 v0 = *reinterpret_cast<const float4*>(&Af32[(size_t)bA * K + kk]);
      const float4 v1 = *reinterpret_cast<const float4*>(&Af32[(size_t)bA * K + kk + 4]);
      split8v(v0, v1, ahi, alo);
    } else {
      ahi = *reinterpret_cast<const bh8*>(&Ahi[(size_t)bA * K + kk]);
      alo = *reinterpret_cast<const bh8*>(&Alo[(size_t)bA * K + kk]);
    }
    // stage W chunk [128][32] f32 via global_load_lds, source pre-swizzled
    #pragma unroll
    for (int q = 0; q < 4; ++q) {
      const int s = (q << 8) + tid;              // float4-slot 0..1023
      const int r = s >> 3;                      // row 0..127
      const int p = s & 7;                       // stored slot
      const float* gp = &W[(size_t)(obase + r) * K + kc + ((p ^ (r & 7)) << 2)];
      gload16(gp, Wt + ((s & ~63) << 2));        // wave-uniform base; HW adds lane*16
    }
    __syncthreads();

    #pragma unroll
    for (int of = 0; of < 4; ++of) {
      const int lr = ow + (of << 4) + l15;
      const int cb = lk << 1;
      const float4 w0 = *reinterpret_cast<const float4*>(
          &Wt[(lr << 5) + ((cb ^ (lr & 7)) << 2)]);
      const float4 w1 = *reinterpret_cast<const float4*>(
          &Wt[(lr << 5) + (((cb + 1) ^ (lr & 7)) << 2)]);
      bh8 whi, wlo;
      split8v(w0, w1, whi, wlo);
      acc[of] = __builtin_amdgcn_mfma_f32_16x16x32_bf16(ahi, whi, acc[of], 0, 0, 0);
      acc[of] = __builtin_amdgcn_mfma_f32_16x16x32_bf16(ahi, wlo, acc[of], 0, 0, 0);
      acc[of] = __builtin_amdgcn_mfma_f32_16x16x32_bf16(alo, whi, acc[of], 0, 0, 0);
    }
    __syncthreads();
  }

  #pragma unroll
  for (int of = 0; of < 4; ++of) {
    const int o = obase + ow + (of << 4) + l15;
    #pragma unroll
    for (int r = 0; r < 4; ++r) {
      const int b = b0 + lk * 4 + r;
      P[((size_t)sl * 32 + b) * O + o] = acc[of][r];
    }
  }
}

// ================= gemm + co-scheduled meta kernel =================
template<int KL, int OBL, int AF32>
__global__ __launch_bounds__(NT) void gemm_meta(
    int nGemm, const float* Af32, const ushort_t* Ahi, const ushort_t* Alo,
    const float* W, int K, int O, float* P,
    int mStart,
    const float* w1, const float* w2, const float* w3,
    const float* a0, const float* a1r, const float* a2r, const float* a3r,
    float* n1, float* n2, float* n3,
    const float* mw1, const float* mb1, const float* mw2, const float* mb2) {
  const int bid = blockIdx.x;
  const int tid = threadIdx.x;
  if (bid < nGemm) {
    __shared__ float Wt[128 * 32];   // 16 KB static; 160/16=10 >= 8 blk/CU -> no cap
    gemm_fwd<KL, OBL, AF32>(bid, tid, Af32, Ahi, Alo, W, K, O, P, Wt);
    return;
  }
  const int g = mStart + (bid - nGemm) * NT + tid;
  meta_body(g, w1, w2, w3, a0, a1r, a2r, a3r, n1, n2, n3, mw1, mb1, mw2, mb2);
}

// ================= meta-only kernel (no LDS) =================
__global__ __launch_bounds__(NT) void meta_only(
    int mStart,
    const float* w1, const float* w2, const float* w3,
    const float* a0, const float* a1r, const float* a2r, const float* a3r,
    float* n1, float* n2, float* n3,
    const float* mw1, const float* mb1, const float* mw2, const float* mb2) {
  const int g = mStart + blockIdx.x * NT + threadIdx.x;
  meta_body(g, w1, w2, w3, a0, a1r, a2r, a3r, n1, n2, n3, mw1, mb1, mw2, mb2);
}

// ================= reduce: 1 element/thread, sums 16 slices =================
// MODE 0: write act hi/lo bf16 + row0. MODE 1: write out f32 + row0.
template<int MODE, int OSH>
__global__ __launch_bounds__(NT) void red_k(
    const float* __restrict__ P, const float* __restrict__ bias,
    ushort_t* __restrict__ aHi, ushort_t* __restrict__ aLo,
    float* __restrict__ outF, float* __restrict__ row0) {
  const int idx = blockIdx.x * NT + threadIdx.x;
  const int b = idx >> OSH;
  const int o = idx & ((1 << OSH) - 1);
  const int O = 1 << OSH;
  float s = 0.f;
  #pragma unroll
  for (int sl = 0; sl < 16; ++sl)
    s += P[(size_t)((sl * 32 + b) << OSH) + o];
  const float v = fmaxf(s + bias[o], 0.f);
  if constexpr (MODE == 0) {
    const uint u = __float_as_uint(v);
    aHi[(size_t)(b << OSH) + o] = (ushort_t)(u >> 16);
    const float hi = __uint_as_float(u & 0xffff0000u);
    aLo[(size_t)(b << OSH) + o] = (ushort_t)(__float_as_uint(v - hi) >> 16);
  } else {
    outF[(size_t)(b << OSH) + o] = v;
  }
  if (b == 0) row0[o] = v;
}

extern "C" void kernel_launch(void* const* d_in, const int* in_sizes, int n_in,
                              void* d_out, int out_size, void* d_ws, size_t ws_size,
                              hipStream_t stream) {
  const float* x   = (const float*)d_in[0];
  const float* w1  = (const float*)d_in[1];
  const float* b1  = (const float*)d_in[2];
  const float* w2  = (const float*)d_in[3];
  const float* b2  = (const float*)d_in[4];
  const float* w3  = (const float*)d_in[5];
  const float* b3  = (const float*)d_in[6];
  const float* mw1 = (const float*)d_in[7];
  const float* mb1 = (const float*)d_in[8];
  const float* mw2 = (const float*)d_in[9];
  const float* mb2 = (const float*)d_in[10];

  float* out = (float*)d_out;                 // [32][1024]
  float* n1  = out + 32 * 1024;               // [2048][1024]
  float* n2  = n1 + 2048 * 1024;              // [2048][2048]
  float* n3  = n2 + 2048 * 2048;              // [1024][2048]

  float* ws = (float*)d_ws;
  float* row01  = ws;                         // 2048
  float* row02  = row01 + 2048;               // 2048
  float* outrow = row02 + 2048;               // 1024
  ushort_t* a1hi = (ushort_t*)(outrow + 1024);
  ushort_t* a1lo = a1hi + 65536;
  ushort_t* a2hi = a1lo + 65536;
  ushort_t* a2lo = a2hi + 65536;
  float* P1 = (float*)(a2lo + 65536);         // [16][32][2048] 4 MB
  float* P2 = P1 + 1048576;                   // 4 MB
  float* P3 = P2 + 1048576;                   // [16][32][1024] 2 MB

  #define MARGS w1, w2, w3, x, row01, row02, outrow, n1, n2, n3, mw1, mb1, mw2, mb2

  // K1: gemm1 x@w1 -> P1 (256 blocks, K=1024, O=2048, KL=64)
  gemm_meta<64, 4, 1><<<256, NT, 0, stream>>>(
      256, x, nullptr, nullptr, w1, 1024, 2048, P1, 0, MARGS);

  // K2: red1 P1 -> a1 bf16 + row01 (256 blocks)
  red_k<0, 11><<<256, NT, 0, stream>>>(P1, b1, a1hi, a1lo, nullptr, row01);

  // K3: gemm2 a1@w2 -> P2 (256) || meta1 g in [0, 262144) (1024)
  gemm_meta<128, 4, 0><<<1280, NT, 0, stream>>>(
      256, nullptr, a1hi, a1lo, w2, 2048, 2048, P2, 0, MARGS);

  // K4: red2 P2 -> a2 bf16 + row02 (256 blocks)
  red_k<0, 11><<<256, NT, 0, stream>>>(P2, b2, a2hi, a2lo, nullptr, row02);

  // K5: gemm3 a2@w3 -> P3 (128) || meta2 g in [262144, 786432) (2048)
  gemm_meta<128, 3, 0><<<2176, NT, 0, stream>>>(
      128, nullptr, a2hi, a2lo, w3, 2048, 1024, P3, 262144, MARGS);

  // K6: red3 P3 -> out f32 + outrow (128 blocks)
  red_k<1, 10><<<128, NT, 0, stream>>>(P3, b3, nullptr, nullptr, out, outrow);

  // K7: meta3 g in [786432, 1048576) (1024 blocks)
  meta_only<<<1024, NT, 0, stream>>>(786432, MARGS);

  #undef MARGS
}